// Round 10
// baseline (307.131 us; speedup 1.0000x reference)
//
#include <hip/hip_runtime.h>

#define NN 8192
#define DDIM 128
#define DELTA 0.0092f   // >= 2*delta_wc + margin; delta_wc <= 2*2^-9 + K*2^-24 ~ 4.0e-3
#define MAXC 256

typedef short short8 __attribute__((ext_vector_type(8)));
typedef float f32x16 __attribute__((ext_vector_type(16)));

__device__ __forceinline__ ushort bf16_rne(float v) {
    const unsigned x = __float_as_uint(v);
    return (ushort)((x + 0x7FFFu + ((x >> 16) & 1u)) >> 16);
}

// ---------------- Kernel 1: MLP (Linear->ReLU->Linear) + L2 normalize + bf16 copy ----
// f32 emb path FROZEN (bit-exact vs round-3/5 passing version); RNE bf16 mirror.
__global__ __launch_bounds__(128, 1)
void mlp_norm_kernel(const float* __restrict__ X, const float* __restrict__ W1,
                     const float* __restrict__ b1, const float* __restrict__ W2,
                     const float* __restrict__ b2, float* __restrict__ emb,
                     ushort* __restrict__ ebh, int rowsPerBlock)
{
    const int t = threadIdx.x;
    float4 w1r[32], w2r[32];
#pragma unroll
    for (int i = 0; i < 32; ++i) w1r[i] = *(const float4*)&W1[t * DDIM + i * 4];
#pragma unroll
    for (int i = 0; i < 32; ++i) w2r[i] = *(const float4*)&W2[t * DDIM + i * 4];
    const float bb1 = b1[t], bb2 = b2[t];

    __shared__ float sx[DDIM];
    __shared__ float sh[DDIM];
    __shared__ float wred[2];

    const int row0 = blockIdx.x * rowsPerBlock;
    for (int r = 0; r < rowsPerBlock; ++r) {
        const int row = row0 + r;
        sx[t] = X[(size_t)row * DDIM + t];
        __syncthreads();
        float acc = bb1;
#pragma unroll
        for (int i = 0; i < 32; ++i) {
            const float4 xv = *(const float4*)&sx[i * 4];
            acc = fmaf(xv.x, w1r[i].x, acc);
            acc = fmaf(xv.y, w1r[i].y, acc);
            acc = fmaf(xv.z, w1r[i].z, acc);
            acc = fmaf(xv.w, w1r[i].w, acc);
        }
        sh[t] = fmaxf(acc, 0.f);
        __syncthreads();
        float acc2 = bb2;
#pragma unroll
        for (int i = 0; i < 32; ++i) {
            const float4 hv = *(const float4*)&sh[i * 4];
            acc2 = fmaf(hv.x, w2r[i].x, acc2);
            acc2 = fmaf(hv.y, w2r[i].y, acc2);
            acc2 = fmaf(hv.z, w2r[i].z, acc2);
            acc2 = fmaf(hv.w, w2r[i].w, acc2);
        }
        float sq = acc2 * acc2;
#pragma unroll
        for (int off = 1; off < 64; off <<= 1) sq += __shfl_xor(sq, off);
        if ((t & 63) == 0) wred[t >> 6] = sq;
        __syncthreads();
        const float ss = wred[0] + wred[1];
        const float inv = 1.0f / fmaxf(sqrtf(ss), 1e-12f);
        const float v = acc2 * inv;
        emb[(size_t)row * DDIM + t] = v;
        ebh[(size_t)row * DDIM + t] = bf16_rne(v);
        __syncthreads();   // protect sx/sh/wred for next iteration
    }
}

// ---------------- Kernel 2: approx sim = ebh @ ebh^T (bf16 MFMA, LDS-free) -----------
// ebh is 2 MB -> resident in every XCD L2 (and largely L1 per tile). Fragments loaded
// DIRECTLY from global (same 16B the LDS path staged -> sims BIT-IDENTICAL to r9).
// No LDS, no barriers; 128x128 tile, 4 waves (2x2), wave tile 64x64; store-wall-bound.
__global__ __launch_bounds__(256, 4)
void simgemm_direct(const ushort* __restrict__ ebh, float* __restrict__ out)
{
    const int tid = threadIdx.x;
    const int bi = blockIdx.x & 63, bj = blockIdx.x >> 6;
    const int m0 = bi << 7, n0 = bj << 7;
    const int lane = tid & 63, wid = tid >> 6;
    const int wr = wid >> 1, wc = wid & 1;
    const int frow = lane & 31, fsel = lane >> 5;

    const ushort* arow0 = ebh + (size_t)(m0 + wr * 64 + frow) * DDIM;
    const ushort* arow1 = arow0 + 32 * DDIM;
    const ushort* brow0 = ebh + (size_t)(n0 + wc * 64 + frow) * DDIM;
    const ushort* brow1 = brow0 + 32 * DDIM;

    f32x16 acc[2][2];
#pragma unroll
    for (int mb = 0; mb < 2; ++mb)
#pragma unroll
        for (int nb = 0; nb < 2; ++nb)
#pragma unroll
            for (int q = 0; q < 16; ++q) acc[mb][nb][q] = 0.f;

#pragma unroll
    for (int ks = 0; ks < 8; ++ks) {           // 8 k-steps of 16 cover K=128
        const int e0 = (ks * 2 + fsel) * 8;    // element offset of this lane's granule
        short8 av[2], bv[2];
        av[0] = *(const short8*)&arow0[e0];
        av[1] = *(const short8*)&arow1[e0];
        bv[0] = *(const short8*)&brow0[e0];
        bv[1] = *(const short8*)&brow1[e0];
#pragma unroll
        for (int mb = 0; mb < 2; ++mb)
#pragma unroll
            for (int nb = 0; nb < 2; ++nb)
                acc[mb][nb] = __builtin_amdgcn_mfma_f32_32x32x16_bf16(
                    av[mb], bv[nb], acc[mb][nb], 0, 0, 0);
    }

    // C/D layout: col = lane&31, row = (q&3) + 8*(q>>2) + 4*(lane>>5)  [verified r7/r9]
#pragma unroll
    for (int mb = 0; mb < 2; ++mb)
#pragma unroll
        for (int nb = 0; nb < 2; ++nb)
#pragma unroll
            for (int q = 0; q < 16; ++q) {
                const int rl = (q & 3) + 8 * (q >> 2) + 4 * fsel;
                const int grow = m0 + wr * 64 + mb * 32 + rl;
                const int gcol = n0 + wc * 64 + nb * 32 + (lane & 31);
                out[(size_t)grow * NN + gcol] = acc[mb][nb][q];
            }
}

// ---------------- Kernel 3: top-kp1 on approx sims + exact fixup + ReLU (in place) ----
// Radix-select with uncertainty-bounded EARLY STOP: after bit b (exponent final) the
// true approx-cut T is in [thr, thr+2^b-1]; once that float-width <= DELTA/4 we stop
// and use window [f(thr)-DELTA, f(thr+2^b-1)+DELTA]. Window entries recomputed EXACTLY
// (frozen fmaf chain from f32 emb == round-3-proven ordering) and ranked.
__global__ __launch_bounds__(256)
void topk_relu_kernel(float* __restrict__ out, const float* __restrict__ emb,
                      const int* __restrict__ kp1p)
{
    const int row = blockIdx.x;
    const int t = threadIdx.x;
    const int w = t >> 6;
    const unsigned kp1 = (unsigned)kp1p[0];
    float* rowp = out + (size_t)row * NN;

    __shared__ unsigned bitmap[NN / 32];   // 1 KB keep-bitmap for window candidates
    __shared__ float semb[DDIM];
    __shared__ unsigned wsum[2][4];
    __shared__ unsigned wmin[4];
    __shared__ int cidx[MAXC];
    __shared__ float cval[MAXC];
    __shared__ int cnum;

    bitmap[t] = 0;
    if (t == 0) cnum = 0;
    if (t < DDIM) semb[t] = emb[(size_t)row * DDIM + t];

    unsigned u[32];
#pragma unroll
    for (int i = 0; i < 8; ++i) {
        const float4 v = *(const float4*)&rowp[(i * 256 + t) * 4];
        u[i * 4 + 0] = v.x > 0.f ? __float_as_uint(v.x) : 0u;
        u[i * 4 + 1] = v.y > 0.f ? __float_as_uint(v.y) : 0u;
        u[i * 4 + 2] = v.z > 0.f ? __float_as_uint(v.z) : 0u;
        u[i * 4 + 3] = v.w > 0.f ? __float_as_uint(v.w) : 0u;
    }

    // ---- radix select (ballot+popcount), exact early-exit OR bracket early-stop ----
    unsigned thr = 0, teff = 0;
    int bexit = 0;
    bool done = false;
    for (int b = 29; b >= 0; --b) {
        const unsigned cand = thr | (1u << b);
        unsigned cnt = 0;
#pragma unroll
        for (int i = 0; i < 32; ++i)
            cnt += (unsigned)__popcll(__ballot(u[i] >= cand));
        if ((t & 63) == 0) wsum[b & 1][w] = cnt;
        __syncthreads();
        const unsigned tot = wsum[b & 1][0] + wsum[b & 1][1] +
                             wsum[b & 1][2] + wsum[b & 1][3];
        if (tot >= kp1) {
            thr = cand;
            if (tot == kp1) {
                // exact: cut = min{u : u >= cand}
                unsigned m = 0xFFFFFFFFu;
#pragma unroll
                for (int i = 0; i < 32; ++i)
                    if (u[i] >= cand && u[i] < m) m = u[i];
#pragma unroll
                for (int off = 1; off < 64; off <<= 1) {
                    const unsigned o = __shfl_xor(m, off);
                    if (o < m) m = o;
                }
                if ((t & 63) == 0) wmin[w] = m;
                __syncthreads();
                unsigned mm = wmin[0];
                if (wmin[1] < mm) mm = wmin[1];
                if (wmin[2] < mm) mm = wmin[2];
                if (wmin[3] < mm) mm = wmin[3];
                teff = mm;
                done = true;
                break;
            }
        }
        // bracket stop: T in [thr, thr + 2^b - 1]; stop when width <= ~DELTA/4
        if (thr != 0u && b <= 22 && (int)(thr >> 23) + b <= 141) { bexit = b; break; }
    }

    // ---- fixup window ----
    unsigned hi_u, lo_u;
    if (thr != 0u) {
        float fLo, fUp;
        if (done) { fLo = fUp = __uint_as_float(teff); }
        else      { fLo = __uint_as_float(thr);
                    fUp = __uint_as_float(thr + (1u << bexit) - 1u); }
        hi_u = __float_as_uint(fUp + DELTA);
        const float lof = fLo - DELTA;
        lo_u = (lof > 0.f) ? __float_as_uint(lof) : 0u;

        // A = #(approx > hi) certainly kept; gather window candidates
        unsigned acnt = 0;
#pragma unroll
        for (int q = 0; q < 32; ++q) {
            const unsigned uu = u[q];
            if (uu > hi_u) ++acnt;
            else if (uu != 0u && uu >= lo_u) {
                const int p = atomicAdd(&cnum, 1);
                if (p < MAXC) cidx[p] = (((q >> 2) * 256 + t) << 2) + (q & 3);
            }
        }
#pragma unroll
        for (int off = 1; off < 64; off <<= 1) acnt += __shfl_xor(acnt, off);
        if ((t & 63) == 0) wsum[0][w] = acnt;
        __syncthreads();
        const unsigned A = wsum[0][0] + wsum[0][1] + wsum[0][2] + wsum[0][3];
        const int nc = cnum < MAXC ? cnum : MAXC;

        // exact recompute: frozen serial fmaf chain, ascending k (== round-3 ordering)
        if (t < nc) {
            const float* rb = emb + (size_t)cidx[t] * DDIM;
            float a = 0.f;
#pragma unroll 8
            for (int k = 0; k < DDIM; ++k) a = fmaf(semb[k], rb[k], a);
            cval[t] = a;
        }
        __syncthreads();
        // rank among candidates (ties -> lower index wins, matching lax.top_k)
        if (t < nc) {
            const float e = cval[t];
            const int my = cidx[t];
            int r = 0;
            for (int d = 0; d < nc; ++d)
                r += (cval[d] > e) || (cval[d] == e && cidx[d] < my);
            if (A + (unsigned)r < kp1)
                atomicOr(&bitmap[my >> 5], 1u << (my & 31));
        }
        __syncthreads();
    } else {
        hi_u = 0u;            // fewer than kp1 positives: keep all positives
        lo_u = 0xFFFFFFFFu;   // disable candidate path
        __syncthreads();
    }

    // ---- write: keep certain-aboves and ranked-in candidates; zero the rest ----
#pragma unroll
    for (int i = 0; i < 8; ++i) {
        float4 o;
#pragma unroll
        for (int j = 0; j < 4; ++j) {
            const unsigned uu = u[i * 4 + j];
            const int idx = (i * 256 + t) * 4 + j;
            const bool keep = (uu > hi_u) ||
                              (uu != 0u && uu >= lo_u &&
                               ((bitmap[idx >> 5] >> (idx & 31)) & 1u));
            (&o.x)[j] = keep ? __uint_as_float(uu) : 0.f;
        }
        *(float4*)&rowp[(i * 256 + t) * 4] = o;
    }
}

extern "C" void kernel_launch(void* const* d_in, const int* in_sizes, int n_in,
                              void* d_out, int out_size, void* d_ws, size_t ws_size,
                              hipStream_t stream)
{
    const float* X  = (const float*)d_in[0];
    const float* W1 = (const float*)d_in[1];
    const float* b1 = (const float*)d_in[2];
    const float* W2 = (const float*)d_in[3];
    const float* b2 = (const float*)d_in[4];
    const int* kp1  = (const int*)d_in[5];
    float* out = (float*)d_out;
    float* emb  = (float*)d_ws;                                   // 4 MB f32
    ushort* ebh = (ushort*)((char*)d_ws + (size_t)NN * DDIM * 4); // 2 MB bf16

    mlp_norm_kernel<<<512, 128, 0, stream>>>(X, W1, b1, W2, b2, emb, ebh, 16);
    simgemm_direct<<<4096, 256, 0, stream>>>(ebh, out);
    topk_relu_kernel<<<NN, 256, 0, stream>>>(out, emb, kp1);
}

// Round 11
// 218.715 us; speedup vs baseline: 1.4043x; 1.4043x over previous
//
#include <hip/hip_runtime.h>
#include <hip/hip_fp16.h>

#define NN 8192
#define DDIM 128
#define DELTA 0.010f    // >= 2*delta_wc; delta_wc <= 2^-8 (bf16 MFMA) + 5e-4 (f16 store)
#define MAXC 256
#define SIMSTRIDE 16384 // ushorts per row slot (= 32 KB = one f32 output row)

typedef short short8 __attribute__((ext_vector_type(8)));
typedef unsigned short ushort8 __attribute__((ext_vector_type(8)));
typedef float f32x16 __attribute__((ext_vector_type(16)));

__device__ __forceinline__ ushort bf16_rne(float v) {
    const unsigned x = __float_as_uint(v);
    return (ushort)((x + 0x7FFFu + ((x >> 16) & 1u)) >> 16);
}

// ---------------- Kernel 1: MLP (Linear->ReLU->Linear) + L2 normalize + bf16 copy ----
// f32 emb path FROZEN (bit-exact vs round-3/5 passing version); RNE bf16 mirror.
__global__ __launch_bounds__(128, 1)
void mlp_norm_kernel(const float* __restrict__ X, const float* __restrict__ W1,
                     const float* __restrict__ b1, const float* __restrict__ W2,
                     const float* __restrict__ b2, float* __restrict__ emb,
                     ushort* __restrict__ ebh, int rowsPerBlock)
{
    const int t = threadIdx.x;
    float4 w1r[32], w2r[32];
#pragma unroll
    for (int i = 0; i < 32; ++i) w1r[i] = *(const float4*)&W1[t * DDIM + i * 4];
#pragma unroll
    for (int i = 0; i < 32; ++i) w2r[i] = *(const float4*)&W2[t * DDIM + i * 4];
    const float bb1 = b1[t], bb2 = b2[t];

    __shared__ float sx[DDIM];
    __shared__ float sh[DDIM];
    __shared__ float wred[2];

    const int row0 = blockIdx.x * rowsPerBlock;
    for (int r = 0; r < rowsPerBlock; ++r) {
        const int row = row0 + r;
        sx[t] = X[(size_t)row * DDIM + t];
        __syncthreads();
        float acc = bb1;
#pragma unroll
        for (int i = 0; i < 32; ++i) {
            const float4 xv = *(const float4*)&sx[i * 4];
            acc = fmaf(xv.x, w1r[i].x, acc);
            acc = fmaf(xv.y, w1r[i].y, acc);
            acc = fmaf(xv.z, w1r[i].z, acc);
            acc = fmaf(xv.w, w1r[i].w, acc);
        }
        sh[t] = fmaxf(acc, 0.f);
        __syncthreads();
        float acc2 = bb2;
#pragma unroll
        for (int i = 0; i < 32; ++i) {
            const float4 hv = *(const float4*)&sh[i * 4];
            acc2 = fmaf(hv.x, w2r[i].x, acc2);
            acc2 = fmaf(hv.y, w2r[i].y, acc2);
            acc2 = fmaf(hv.z, w2r[i].z, acc2);
            acc2 = fmaf(hv.w, w2r[i].w, acc2);
        }
        float sq = acc2 * acc2;
#pragma unroll
        for (int off = 1; off < 64; off <<= 1) sq += __shfl_xor(sq, off);
        if ((t & 63) == 0) wred[t >> 6] = sq;
        __syncthreads();
        const float ss = wred[0] + wred[1];
        const float inv = 1.0f / fmaxf(sqrtf(ss), 1e-12f);
        const float v = acc2 * inv;
        emb[(size_t)row * DDIM + t] = v;
        ebh[(size_t)row * DDIM + t] = bf16_rne(v);
        __syncthreads();   // protect sx/sh/wred for next iteration
    }
}

// ---------------- Kernel 2: approx sim = ebh @ ebh^T (bf16 MFMA, f16 store in d_out) --
// r9's proven LDS structure (fastest measured GEMM); store halved to f16. Row r's f16
// sims occupy the FIRST 16 KB of output row r's 32 KB slot (topk reads then overwrites
// its own slot only -> deterministic). 128x128 tile, 4 waves (2x2), single barrier.
__global__ __launch_bounds__(256)
void simgemm_bf16(const ushort* __restrict__ ebh, ushort* __restrict__ sim)
{
    __shared__ ushort lA[128 * 128];
    __shared__ ushort lB[128 * 128];

    const int tid = threadIdx.x;
    const int bi = blockIdx.x & 63, bj = blockIdx.x >> 6;
    const int m0 = bi << 7, n0 = bj << 7;
    const int lane = tid & 63, wid = tid >> 6;
    const int wr = wid >> 1, wc = wid & 1;
    const int frow = lane & 31, fsel = lane >> 5;

    const int srow0 = tid >> 4, sg = tid & 15;
#pragma unroll
    for (int i = 0; i < 8; ++i) {
        const int row = srow0 + i * 16;
        const int so = row * 128 + ((sg ^ (row & 15)) << 3);
        *(uint4*)&lA[so] = *(const uint4*)&ebh[(size_t)(m0 + row) * DDIM + sg * 8];
        *(uint4*)&lB[so] = *(const uint4*)&ebh[(size_t)(n0 + row) * DDIM + sg * 8];
    }
    __syncthreads();

    f32x16 acc[2][2];
#pragma unroll
    for (int mb = 0; mb < 2; ++mb)
#pragma unroll
        for (int nb = 0; nb < 2; ++nb)
#pragma unroll
            for (int q = 0; q < 16; ++q) acc[mb][nb][q] = 0.f;

#pragma unroll
    for (int ks = 0; ks < 8; ++ks) {
        const int g = ks * 2 + fsel;
        short8 av[2], bv[2];
#pragma unroll
        for (int mb = 0; mb < 2; ++mb) {
            const int r = wr * 64 + mb * 32 + frow;
            av[mb] = *(const short8*)&lA[r * 128 + ((g ^ (r & 15)) << 3)];
        }
#pragma unroll
        for (int nb = 0; nb < 2; ++nb) {
            const int r = wc * 64 + nb * 32 + frow;
            bv[nb] = *(const short8*)&lB[r * 128 + ((g ^ (r & 15)) << 3)];
        }
#pragma unroll
        for (int mb = 0; mb < 2; ++mb)
#pragma unroll
            for (int nb = 0; nb < 2; ++nb)
                acc[mb][nb] = __builtin_amdgcn_mfma_f32_32x32x16_bf16(
                    av[mb], bv[nb], acc[mb][nb], 0, 0, 0);
    }

    // C/D layout: col = lane&31, row = (q&3) + 8*(q>>2) + 4*(lane>>5)  [verified r7/r9]
#pragma unroll
    for (int mb = 0; mb < 2; ++mb)
#pragma unroll
        for (int nb = 0; nb < 2; ++nb)
#pragma unroll
            for (int q = 0; q < 16; ++q) {
                const int rl = (q & 3) + 8 * (q >> 2) + 4 * fsel;
                const int grow = m0 + wr * 64 + mb * 32 + rl;
                const int gcol = n0 + wc * 64 + nb * 32 + (lane & 31);
                sim[(size_t)grow * SIMSTRIDE + gcol] =
                    __half_as_ushort(__float2half_rn(acc[mb][nb][q]));
            }
}

// ---------------- Kernel 3: top-kp1 on f16 sims + exact fixup + f32 ReLU write -------
// 14-bit radix on raw f16 bits (positive f16 compares as ushort). Cut T_b exact in f16
// space; window [T-DELTA, T+DELTA] (f16 bounds padded +-1 ulp) recomputed EXACTLY
// (frozen fmaf chain from f32 emb == round-3-proven ordering) and ranked.
// Reads its own row's f16 data (first 16 KB of slot), then overwrites slot with f32.
__global__ __launch_bounds__(256)
void topk_relu_kernel(float* __restrict__ out, const float* __restrict__ emb,
                      const int* __restrict__ kp1p)
{
    const int row = blockIdx.x;
    const int t = threadIdx.x;
    const int w = t >> 6;
    const unsigned kp1 = (unsigned)kp1p[0];
    const ushort* simrow = (const ushort*)out + (size_t)row * SIMSTRIDE;
    float* rowp = out + (size_t)row * NN;

    __shared__ unsigned bitmap[NN / 32];
    __shared__ float semb[DDIM];
    __shared__ unsigned wsum[2][4];
    __shared__ unsigned wmin[4];
    __shared__ int cidx[MAXC];
    __shared__ float cval[MAXC];
    __shared__ int cnum;

    bitmap[t] = 0;
    if (t == 0) cnum = 0;
    if (t < DDIM) semb[t] = emb[(size_t)row * DDIM + t];

    // load 32 f16 values/thread (coalesced 16B), zero non-positives
    unsigned u[32];
#pragma unroll
    for (int i = 0; i < 4; ++i) {
        const ushort8 v8 = *(const ushort8*)&simrow[i * 2048 + t * 8];
#pragma unroll
        for (int j = 0; j < 8; ++j)
            u[i * 8 + j] = (v8[j] < 0x8000u) ? (unsigned)v8[j] : 0u;
    }

    // ---- 14-bit radix select (ballot+popcount), exact early-exit ----
    unsigned thr = 0, teff = 0;
    bool done = false;
    for (int b = 13; b >= 0; --b) {
        const unsigned cand = thr | (1u << b);
        unsigned cnt = 0;
#pragma unroll
        for (int i = 0; i < 32; ++i)
            cnt += (unsigned)__popcll(__ballot(u[i] >= cand));
        if ((t & 63) == 0) wsum[b & 1][w] = cnt;
        __syncthreads();
        const unsigned tot = wsum[b & 1][0] + wsum[b & 1][1] +
                             wsum[b & 1][2] + wsum[b & 1][3];
        if (tot >= kp1) {
            thr = cand;
            if (tot == kp1) {
                unsigned m = 0xFFFFFFFFu;
#pragma unroll
                for (int i = 0; i < 32; ++i)
                    if (u[i] >= cand && u[i] < m) m = u[i];
#pragma unroll
                for (int off = 1; off < 64; off <<= 1) {
                    const unsigned o = __shfl_xor(m, off);
                    if (o < m) m = o;
                }
                if ((t & 63) == 0) wmin[w] = m;
                __syncthreads();
                unsigned mm = wmin[0];
                if (wmin[1] < mm) mm = wmin[1];
                if (wmin[2] < mm) mm = wmin[2];
                if (wmin[3] < mm) mm = wmin[3];
                teff = mm;
                done = true;
                break;
            }
        }
    }
    if (!done) teff = thr;   // full radix: thr == exact kp1-th largest f16 value
    __syncthreads();         // fence: wsum[0] reused below; last round may read slot 0

    // ---- fixup window (f16-bit domain, +-1 ulp conservative padding) ----
    unsigned hi16, lo16;
    if (thr != 0u) {
        const float Treal = __half2float(__ushort_as_half((ushort)teff));
        hi16 = (unsigned)__half_as_ushort(__float2half_rn(Treal + DELTA)) + 1u;
        const float loR = Treal - DELTA;
        if (loR <= 0.f) lo16 = 1u;
        else {
            const unsigned l = __half_as_ushort(__float2half_rn(loR));
            lo16 = (l > 1u) ? l - 1u : 1u;
        }

        // A = #(v > hi) certainly kept; gather window candidates
        unsigned acnt = 0;
#pragma unroll
        for (int q = 0; q < 32; ++q) {
            const unsigned uu = u[q];
            if (uu > hi16) ++acnt;
            else if (uu >= lo16) {
                const int p = atomicAdd(&cnum, 1);
                if (p < MAXC) cidx[p] = (q >> 3) * 2048 + t * 8 + (q & 7);
            }
        }
#pragma unroll
        for (int off = 1; off < 64; off <<= 1) acnt += __shfl_xor(acnt, off);
        if ((t & 63) == 0) wsum[0][w] = acnt;
        __syncthreads();
        const unsigned A = wsum[0][0] + wsum[0][1] + wsum[0][2] + wsum[0][3];
        const int nc = cnum < MAXC ? cnum : MAXC;

        // exact recompute: frozen serial fmaf chain, ascending k (== round-3 ordering)
        if (t < nc) {
            const float* rb = emb + (size_t)cidx[t] * DDIM;
            float a = 0.f;
#pragma unroll 8
            for (int k = 0; k < DDIM; ++k) a = fmaf(semb[k], rb[k], a);
            cval[t] = a;
        }
        __syncthreads();
        // rank among candidates (ties -> lower index wins, matching lax.top_k)
        if (t < nc) {
            const float e = cval[t];
            const int my = cidx[t];
            int r = 0;
            for (int d = 0; d < nc; ++d)
                r += (cval[d] > e) || (cval[d] == e && cidx[d] < my);
            if (A + (unsigned)r < kp1)
                atomicOr(&bitmap[my >> 5], 1u << (my & 31));
        }
        __syncthreads();
    } else {
        hi16 = 0u;       // fewer than kp1 positives: keep all positives (v > 0)
        lo16 = 0xFFFFu;  // disable window path
        __syncthreads();
    }

    // ---- write full f32 row: certain-aboves + ranked-in candidates; zeros elsewhere --
#pragma unroll
    for (int i = 0; i < 4; ++i) {
        const int col0 = i * 2048 + t * 8;
        float o[8];
#pragma unroll
        for (int j = 0; j < 8; ++j) {
            const unsigned uu = u[i * 8 + j];
            const int idx = col0 + j;
            const bool keep = (uu > hi16) ||
                              (uu >= lo16 &&
                               ((bitmap[idx >> 5] >> (idx & 31)) & 1u));
            o[j] = keep ? __half2float(__ushort_as_half((ushort)uu)) : 0.f;
        }
        *(float4*)&rowp[col0]     = make_float4(o[0], o[1], o[2], o[3]);
        *(float4*)&rowp[col0 + 4] = make_float4(o[4], o[5], o[6], o[7]);
    }
}

extern "C" void kernel_launch(void* const* d_in, const int* in_sizes, int n_in,
                              void* d_out, int out_size, void* d_ws, size_t ws_size,
                              hipStream_t stream)
{
    const float* X  = (const float*)d_in[0];
    const float* W1 = (const float*)d_in[1];
    const float* b1 = (const float*)d_in[2];
    const float* W2 = (const float*)d_in[3];
    const float* b2 = (const float*)d_in[4];
    const int* kp1  = (const int*)d_in[5];
    float* out = (float*)d_out;
    float* emb  = (float*)d_ws;                                   // 4 MB f32
    ushort* ebh = (ushort*)((char*)d_ws + (size_t)NN * DDIM * 4); // 2 MB bf16

    mlp_norm_kernel<<<512, 128, 0, stream>>>(X, W1, b1, W2, b2, emb, ebh, 16);
    simgemm_bf16<<<4096, 256, 0, stream>>>(ebh, (ushort*)out);
    topk_relu_kernel<<<NN, 256, 0, stream>>>(out, emb, kp1);
}

// Round 12
// 202.684 us; speedup vs baseline: 1.5153x; 1.0791x over previous
//
#include <hip/hip_runtime.h>
#include <hip/hip_fp16.h>

#define NN 8192
#define DDIM 128
#define DELTA 0.010f    // >= 2*delta_wc; delta_wc <= 2^-8 (bf16 MFMA) + 5e-4 (f16 store)
#define MAXC 256
#define SIMSTRIDE 16384 // ushorts per row slot (= 32 KB = one f32 output row)

typedef short short8 __attribute__((ext_vector_type(8)));
typedef unsigned short ushort8 __attribute__((ext_vector_type(8)));
typedef float f32x16 __attribute__((ext_vector_type(16)));

__device__ __forceinline__ ushort bf16_rne(float v) {
    const unsigned x = __float_as_uint(v);
    return (ushort)((x + 0x7FFFu + ((x >> 16) & 1u)) >> 16);
}

// ---------------- Kernel 1: MLP (Linear->ReLU->Linear) + L2 normalize + bf16 copy ----
// f32 emb path FROZEN (bit-exact vs round-3/5 passing version); RNE bf16 mirror.
__global__ __launch_bounds__(128, 1)
void mlp_norm_kernel(const float* __restrict__ X, const float* __restrict__ W1,
                     const float* __restrict__ b1, const float* __restrict__ W2,
                     const float* __restrict__ b2, float* __restrict__ emb,
                     ushort* __restrict__ ebh, int rowsPerBlock)
{
    const int t = threadIdx.x;
    float4 w1r[32], w2r[32];
#pragma unroll
    for (int i = 0; i < 32; ++i) w1r[i] = *(const float4*)&W1[t * DDIM + i * 4];
#pragma unroll
    for (int i = 0; i < 32; ++i) w2r[i] = *(const float4*)&W2[t * DDIM + i * 4];
    const float bb1 = b1[t], bb2 = b2[t];

    __shared__ float sx[DDIM];
    __shared__ float sh[DDIM];
    __shared__ float wred[2];

    const int row0 = blockIdx.x * rowsPerBlock;
    for (int r = 0; r < rowsPerBlock; ++r) {
        const int row = row0 + r;
        sx[t] = X[(size_t)row * DDIM + t];
        __syncthreads();
        float acc = bb1;
#pragma unroll
        for (int i = 0; i < 32; ++i) {
            const float4 xv = *(const float4*)&sx[i * 4];
            acc = fmaf(xv.x, w1r[i].x, acc);
            acc = fmaf(xv.y, w1r[i].y, acc);
            acc = fmaf(xv.z, w1r[i].z, acc);
            acc = fmaf(xv.w, w1r[i].w, acc);
        }
        sh[t] = fmaxf(acc, 0.f);
        __syncthreads();
        float acc2 = bb2;
#pragma unroll
        for (int i = 0; i < 32; ++i) {
            const float4 hv = *(const float4*)&sh[i * 4];
            acc2 = fmaf(hv.x, w2r[i].x, acc2);
            acc2 = fmaf(hv.y, w2r[i].y, acc2);
            acc2 = fmaf(hv.z, w2r[i].z, acc2);
            acc2 = fmaf(hv.w, w2r[i].w, acc2);
        }
        float sq = acc2 * acc2;
#pragma unroll
        for (int off = 1; off < 64; off <<= 1) sq += __shfl_xor(sq, off);
        if ((t & 63) == 0) wred[t >> 6] = sq;
        __syncthreads();
        const float ss = wred[0] + wred[1];
        const float inv = 1.0f / fmaxf(sqrtf(ss), 1e-12f);
        const float v = acc2 * inv;
        emb[(size_t)row * DDIM + t] = v;
        ebh[(size_t)row * DDIM + t] = bf16_rne(v);
        __syncthreads();   // protect sx/sh/wred for next iteration
    }
}

// ---------------- Kernel 2: approx sim = ebh @ ebh^T (bf16 MFMA, f16 store in d_out) --
// UNCHANGED from round-11 passing version (sims bit-identical).
__global__ __launch_bounds__(256)
void simgemm_bf16(const ushort* __restrict__ ebh, ushort* __restrict__ sim)
{
    __shared__ ushort lA[128 * 128];
    __shared__ ushort lB[128 * 128];

    const int tid = threadIdx.x;
    const int bi = blockIdx.x & 63, bj = blockIdx.x >> 6;
    const int m0 = bi << 7, n0 = bj << 7;
    const int lane = tid & 63, wid = tid >> 6;
    const int wr = wid >> 1, wc = wid & 1;
    const int frow = lane & 31, fsel = lane >> 5;

    const int srow0 = tid >> 4, sg = tid & 15;
#pragma unroll
    for (int i = 0; i < 8; ++i) {
        const int row = srow0 + i * 16;
        const int so = row * 128 + ((sg ^ (row & 15)) << 3);
        *(uint4*)&lA[so] = *(const uint4*)&ebh[(size_t)(m0 + row) * DDIM + sg * 8];
        *(uint4*)&lB[so] = *(const uint4*)&ebh[(size_t)(n0 + row) * DDIM + sg * 8];
    }
    __syncthreads();

    f32x16 acc[2][2];
#pragma unroll
    for (int mb = 0; mb < 2; ++mb)
#pragma unroll
        for (int nb = 0; nb < 2; ++nb)
#pragma unroll
            for (int q = 0; q < 16; ++q) acc[mb][nb][q] = 0.f;

#pragma unroll
    for (int ks = 0; ks < 8; ++ks) {
        const int g = ks * 2 + fsel;
        short8 av[2], bv[2];
#pragma unroll
        for (int mb = 0; mb < 2; ++mb) {
            const int r = wr * 64 + mb * 32 + frow;
            av[mb] = *(const short8*)&lA[r * 128 + ((g ^ (r & 15)) << 3)];
        }
#pragma unroll
        for (int nb = 0; nb < 2; ++nb) {
            const int r = wc * 64 + nb * 32 + frow;
            bv[nb] = *(const short8*)&lB[r * 128 + ((g ^ (r & 15)) << 3)];
        }
#pragma unroll
        for (int mb = 0; mb < 2; ++mb)
#pragma unroll
            for (int nb = 0; nb < 2; ++nb)
                acc[mb][nb] = __builtin_amdgcn_mfma_f32_32x32x16_bf16(
                    av[mb], bv[nb], acc[mb][nb], 0, 0, 0);
    }

    // C/D layout: col = lane&31, row = (q&3) + 8*(q>>2) + 4*(lane>>5)  [verified r7/r9]
#pragma unroll
    for (int mb = 0; mb < 2; ++mb)
#pragma unroll
        for (int nb = 0; nb < 2; ++nb)
#pragma unroll
            for (int q = 0; q < 16; ++q) {
                const int rl = (q & 3) + 8 * (q >> 2) + 4 * fsel;
                const int grow = m0 + wr * 64 + mb * 32 + rl;
                const int gcol = n0 + wc * 64 + nb * 32 + (lane & 31);
                sim[(size_t)grow * SIMSTRIDE + gcol] =
                    __half_as_ushort(__float2half_rn(acc[mb][nb][q]));
            }
}

// ---------------- Kernel 3: top-kp1 on f16 sims (2-level histogram select) + fixup ----
// Select: (1) 256-bin histogram of f16 bits [13:6] (positives only; all bins < 241),
// block suffix-scan -> boundary bin B + count-above A; (2) 64-bin histogram of bin-B
// low 6 bits -> EXACT kp1-th largest f16 value (bit-identical to r11's radix result).
// Window/fixup/write identical to round-11 passing version.
__global__ __launch_bounds__(256)
void topk_relu_kernel(float* __restrict__ out, const float* __restrict__ emb,
                      const int* __restrict__ kp1p)
{
    const int row = blockIdx.x;
    const int t = threadIdx.x;
    const int w = t >> 6;
    const int lane = t & 63;
    const unsigned kp1 = (unsigned)kp1p[0];
    const ushort* simrow = (const ushort*)out + (size_t)row * SIMSTRIDE;
    float* rowp = out + (size_t)row * NN;

    __shared__ unsigned bitmap[NN / 32];
    __shared__ float semb[DDIM];
    __shared__ unsigned hist[4][256];
    __shared__ unsigned h2[64];
    __shared__ unsigned wpart[4];
    __shared__ unsigned sBA[4];     // 0: binB, 1: A(above), 2: teff, 3: keepall flag
    __shared__ int cidx[MAXC];
    __shared__ float cval[MAXC];
    __shared__ int cnum;

    bitmap[t] = 0;
    hist[0][t] = 0; hist[1][t] = 0; hist[2][t] = 0; hist[3][t] = 0;
    if (t < 64) h2[t] = 0;
    if (t < 4) sBA[t] = 0;
    if (t == 0) cnum = 0;
    if (t < DDIM) semb[t] = emb[(size_t)row * DDIM + t];
    __syncthreads();

    // load 32 f16/thread (coalesced 16B), zero non-positives, level-1 histogram
    unsigned u[32];
#pragma unroll
    for (int i = 0; i < 4; ++i) {
        const ushort8 v8 = *(const ushort8*)&simrow[i * 2048 + t * 8];
#pragma unroll
        for (int j = 0; j < 8; ++j) {
            const unsigned uu = (v8[j] < 0x8000u) ? (unsigned)v8[j] : 0u;
            u[i * 8 + j] = uu;
            if (uu) atomicAdd(&hist[w][uu >> 6], 1u);
        }
    }
    __syncthreads();

    // ---- level-1: suffix scan over 256 bins (thread t owns bin t) ----
    const unsigned tot = hist[0][t] + hist[1][t] + hist[2][t] + hist[3][t];
    unsigned s = tot;
#pragma unroll
    for (int off = 1; off < 64; off <<= 1) {
        const unsigned o = __shfl_down(s, off);
        if (lane + off < 64) s += o;
    }
    if (lane == 0) wpart[w] = s;
    __syncthreads();
    unsigned addhi = 0;
    for (int w2 = w + 1; w2 < 4; ++w2) addhi += wpart[w2];
    const unsigned S = s + addhi;               // inclusive suffix: count(bin >= t)
    if (S >= kp1 && S - tot < kp1) { sBA[0] = (unsigned)t; sBA[1] = S - tot; }
    if (t == 0 && wpart[0] + wpart[1] + wpart[2] + wpart[3] < kp1) sBA[3] = 1u;
    __syncthreads();

    const bool keepall = (sBA[3] != 0u);
    if (!keepall) {
        // ---- level-2: 64-bin histogram of bin-B values' low 6 bits ----
        const unsigned binB = sBA[0];
#pragma unroll
        for (int q = 0; q < 32; ++q)
            if (u[q] && (u[q] >> 6) == binB) atomicAdd(&h2[u[q] & 63u], 1u);
        __syncthreads();
        if (t < 64) {
            const unsigned need = kp1 - sBA[1];
            const unsigned h = h2[t];
            unsigned s2 = h;
#pragma unroll
            for (int off = 1; off < 64; off <<= 1) {
                const unsigned o = __shfl_down(s2, off);
                if (t + off < 64) s2 += o;
            }
            if (s2 >= need && s2 - h < need) sBA[2] = (binB << 6) | (unsigned)t;
        }
        __syncthreads();
    }

    // ---- fixup window (identical to r11) ----
    unsigned hi16, lo16;
    if (!keepall) {
        const unsigned teff = sBA[2];
        const float Treal = __half2float(__ushort_as_half((ushort)teff));
        hi16 = (unsigned)__half_as_ushort(__float2half_rn(Treal + DELTA)) + 1u;
        const float loR = Treal - DELTA;
        if (loR <= 0.f) lo16 = 1u;
        else {
            const unsigned l = __half_as_ushort(__float2half_rn(loR));
            lo16 = (l > 1u) ? l - 1u : 1u;
        }

        unsigned acnt = 0;
#pragma unroll
        for (int q = 0; q < 32; ++q) {
            const unsigned uu = u[q];
            if (uu > hi16) ++acnt;
            else if (uu >= lo16) {
                const int p = atomicAdd(&cnum, 1);
                if (p < MAXC) cidx[p] = (q >> 3) * 2048 + t * 8 + (q & 7);
            }
        }
#pragma unroll
        for (int off = 1; off < 64; off <<= 1) acnt += __shfl_xor(acnt, off);
        if (lane == 0) wpart[w] = acnt;
        __syncthreads();
        const unsigned A = wpart[0] + wpart[1] + wpart[2] + wpart[3];
        const int nc = cnum < MAXC ? cnum : MAXC;

        // exact recompute: frozen serial fmaf chain, ascending k (== round-3 ordering)
        if (t < nc) {
            const float* rb = emb + (size_t)cidx[t] * DDIM;
            float a = 0.f;
#pragma unroll 8
            for (int k = 0; k < DDIM; ++k) a = fmaf(semb[k], rb[k], a);
            cval[t] = a;
        }
        __syncthreads();
        // rank among candidates (ties -> lower index wins, matching lax.top_k)
        if (t < nc) {
            const float e = cval[t];
            const int my = cidx[t];
            int r = 0;
            for (int d = 0; d < nc; ++d)
                r += (cval[d] > e) || (cval[d] == e && cidx[d] < my);
            if (A + (unsigned)r < kp1)
                atomicOr(&bitmap[my >> 5], 1u << (my & 31));
        }
        __syncthreads();
    } else {
        hi16 = 0u;       // fewer than kp1 positives: keep all positives (v > 0)
        lo16 = 0xFFFFu;  // disable window path
        __syncthreads();
    }

    // ---- write full f32 row: certain-aboves + ranked-in candidates; zeros elsewhere --
#pragma unroll
    for (int i = 0; i < 4; ++i) {
        const int col0 = i * 2048 + t * 8;
        float o[8];
#pragma unroll
        for (int j = 0; j < 8; ++j) {
            const unsigned uu = u[i * 8 + j];
            const int idx = col0 + j;
            const bool keep = (uu > hi16) ||
                              (uu >= lo16 &&
                               ((bitmap[idx >> 5] >> (idx & 31)) & 1u));
            o[j] = keep ? __half2float(__ushort_as_half((ushort)uu)) : 0.f;
        }
        *(float4*)&rowp[col0]     = make_float4(o[0], o[1], o[2], o[3]);
        *(float4*)&rowp[col0 + 4] = make_float4(o[4], o[5], o[6], o[7]);
    }
}

extern "C" void kernel_launch(void* const* d_in, const int* in_sizes, int n_in,
                              void* d_out, int out_size, void* d_ws, size_t ws_size,
                              hipStream_t stream)
{
    const float* X  = (const float*)d_in[0];
    const float* W1 = (const float*)d_in[1];
    const float* b1 = (const float*)d_in[2];
    const float* W2 = (const float*)d_in[3];
    const float* b2 = (const float*)d_in[4];
    const int* kp1  = (const int*)d_in[5];
    float* out = (float*)d_out;
    float* emb  = (float*)d_ws;                                   // 4 MB f32
    ushort* ebh = (ushort*)((char*)d_ws + (size_t)NN * DDIM * 4); // 2 MB bf16

    mlp_norm_kernel<<<512, 128, 0, stream>>>(X, W1, b1, W2, b2, emb, ebh, 16);
    simgemm_bf16<<<4096, 256, 0, stream>>>(ebh, (ushort*)out);
    topk_relu_kernel<<<NN, 256, 0, stream>>>(out, emb, kp1);
}